// Round 18
// baseline (159.641 us; speedup 1.0000x reference)
//
#include <hip/hip_runtime.h>
#include <hip/hip_bf16.h>

#define SCOPE 63
#define BLOCK_THREADS 256
#define ROWS_PER_WAVE 32
#define ROWS_PER_BLOCK 128
#define NOUT 32

// ---------------------------------------------------------------------------
// Kernel 1: inverse filter g = IFFT( 1 / FFT(delta - f) ) in fp64. Negligible.
// ---------------------------------------------------------------------------
__global__ void compute_inverse_filter(const float* __restrict__ f,
                                       float* __restrict__ g) {
    __shared__ double hre[SCOPE];
    __shared__ double him[SCOPE];
    const double TWO_PI = 6.283185307179586476925286766559;
    int t = threadIdx.x;
    if (t < SCOPE) {
        double re = 0.0, im = 0.0;
        for (int n = 0; n < SCOPE; ++n) {
            double x = (n == 0 ? 1.0 : 0.0) - (double)f[n];
            double ang = -TWO_PI * (double)(t * n) / (double)SCOPE;
            re += x * cos(ang);
            im += x * sin(ang);
        }
        double d = re * re + im * im;
        hre[t] = re / d;
        him[t] = -im / d;
    }
    __syncthreads();
    if (t < SCOPE) {
        double acc = 0.0;
        for (int k = 0; k < SCOPE; ++k) {
            double ang = TWO_PI * (double)(k * t) / (double)SCOPE;
            acc += hre[k] * cos(ang) - him[k] * sin(ang);
        }
        g[t] = (float)(acc / (double)SCOPE);
    }
}

// ---------------------------------------------------------------------------
// Compile-time-unrolled helpers (static indices only -> SROA to registers).
// ---------------------------------------------------------------------------
template <int J0, int J1>
struct LoadSegStop {
    template <int J>
    struct Step {
        __device__ static inline void run(float (&d)[SCOPE], const float* p) {
            if constexpr (J >= J0) {
                Step<J - 1>::run(d, p);
                d[J] = p[J - J0];
            }
        }
    };
    __device__ static inline void run(float (&d)[SCOPE], const float* p) {
        Step<J1>::run(d, p);
    }
};

template <int M, int I>
struct TapRow {
    __device__ static inline void run(float (&acc)[NOUT], const float (&a)[SCOPE],
                                      float gm) {
        TapRow<M, I - 1>::run(acc, a, gm);
        acc[I] += gm * a[(I - M + SCOPE) % SCOPE];
    }
};
template <int M>
struct TapRow<M, -1> {
    __device__ static inline void run(float (&)[NOUT], const float (&)[SCOPE], float) {}
};

template <int M>
struct TapLoop {
    __device__ static inline void run(float (&acc)[NOUT], const float (&a)[SCOPE],
                                      const float* gs) {
        TapLoop<M - 1>::run(acc, a, gs);
        const float gm = gs[M];
        TapRow<M, NOUT - 1>::run(acc, a, gm);
    }
};
template <>
struct TapLoop<0> {
    __device__ static inline void run(float (&acc)[NOUT], const float (&a)[SCOPE],
                                      const float* gs) {
        const float g0 = gs[0];
#pragma unroll
        for (int i = 0; i < NOUT; ++i) acc[i] = g0 * a[i];
    }
};

// Store acc[0..I] to q (static offsets; compiler merges to dwordx4).
template <int I>
struct StoreSeg {
    __device__ static inline void run(float* q, const float (&acc)[NOUT]) {
        StoreSeg<I - 1>::run(q, acc);
        q[I] = acc[I];
    }
};
template <>
struct StoreSeg<-1> {
    __device__ static inline void run(float*, const float (&)[NOUT]) {}
};

// ---------------------------------------------------------------------------
// Kernel 2: BARRIER-FREE direct-register circular convolution.
//
// The 6-round evidence: every barriered-LDS-tile variant pins at 95-127 us
// with wave lifetime ~9.5 us vs 1.7 us of FMA (82% barrier wait). Rows are
// 252 B and lane-private — no cross-lane reuse justifies LDS staging
// (Common-mistake #7). So: each lane loads its row STRAIGHT from global
// into registers (rotated by 32h, two bases, static offsets -> dwordx4
// merges; the wave's 16 KB footprint is fully line-covered, L1 serves the
// 2-lanes-per-row overlap), convolves in registers, stores its contiguous
// 128 B output run directly. No barriers -> no phase lockstep; waves run
// independently and TLP (4 waves/SIMD at ~110 VGPR) hides HBM latency.
//
// Lane l: r = l&31 (row in wave's 32), h = l>>5 (output half).
//   a_rot[k] = row[(32h + k) mod 63]
//   out[32h + i] = sum_m g[m] * a_rot[(i - m) mod 63],  i = 0..31 (31 if h=1)
// ---------------------------------------------------------------------------
__global__ void __launch_bounds__(BLOCK_THREADS)
circ_conv_kernel(const float* __restrict__ A,
                 const float* __restrict__ G,
                 float* __restrict__ O) {
    __shared__ float gs[SCOPE];

    const int tid = threadIdx.x;
    const int w   = tid >> 6;        // wave in block
    const int l   = tid & 63;        // lane in wave
    const int r   = l & 31;          // row within wave's 32
    const int h   = l >> 5;          // output half

    if (tid < SCOPE) gs[tid] = G[tid];
    __syncthreads();                 // one tiny barrier for the 252 B filter

    const long long row = (long long)blockIdx.x * ROWS_PER_BLOCK
                        + w * ROWS_PER_WAVE + r;
    const float* __restrict__ rowp = A + row * SCOPE;
    float* __restrict__ outp       = O + row * SCOPE;

    // ---- rotated row load DIRECT from global: 2 bases, static offsets ----
    const float* q1 = rowp + 32 * h;        // k in [0,31)
    const float* q2 = rowp + 31 - 31 * h;   // k in [31,63)
    float a[SCOPE];
    LoadSegStop<0, 30>::run(a, q1);
    LoadSegStop<31, 62>::run(a, q2);

    // ---- 63-tap convolution into 32 register accumulators ----
    float acc[NOUT];
    TapLoop<SCOPE - 1>::run(acc, a, gs);

    // ---- direct store of the lane's contiguous output run ----
    float* qo = outp + 32 * h;
    StoreSeg<30>::run(qo, acc);
    if (h == 0) qo[31] = acc[31];   // half 1 has only 31 outputs
}

// ---------------------------------------------------------------------------
extern "C" void kernel_launch(void* const* d_in, const int* in_sizes, int n_in,
                              void* d_out, int out_size, void* d_ws, size_t ws_size,
                              hipStream_t stream) {
    const float* activations = (const float*)d_in[0];
    const float* filt        = (const float*)d_in[1];
    float* out               = (float*)d_out;
    float* g                 = (float*)d_ws;   // 63 floats of scratch

    hipLaunchKernelGGL(compute_inverse_filter, dim3(1), dim3(64), 0, stream,
                       filt, g);

    const long long total = (long long)in_sizes[0];
    const long long rows  = total / SCOPE;                 // 524288
    const int blocks      = (int)(rows / ROWS_PER_BLOCK);  // 4096, exact

    hipLaunchKernelGGL(circ_conv_kernel, dim3(blocks), dim3(BLOCK_THREADS), 0,
                       stream, activations, g, out);
}

// Round 19
// 91.752 us; speedup vs baseline: 1.7399x; 1.7399x over previous
//
#include <hip/hip_runtime.h>
#include <hip/hip_bf16.h>

#define SCOPE 63
#define BLOCK_THREADS 256
#define ROWS_PER_BLOCK 128
#define TILE_ELEMS (ROWS_PER_BLOCK * SCOPE)   // 8064 floats

typedef __attribute__((ext_vector_type(8))) __bf16 v8bf;
typedef __attribute__((ext_vector_type(4))) float f32x4;

// async global->LDS, 16B per lane; LDS dest is wave-uniform base + lane*16
#define GLL(gp, lp) __builtin_amdgcn_global_load_lds(                         \
    (const __attribute__((address_space(1))) void*)(gp),                      \
    (__attribute__((address_space(3))) void*)(lp), 16, 0, 0)

// ---------------------------------------------------------------------------
// Kernel 1: inverse filter g = IFFT( 1 / FFT(delta - f) ) in fp64. Negligible.
// ---------------------------------------------------------------------------
__global__ void compute_inverse_filter(const float* __restrict__ f,
                                       float* __restrict__ g) {
    __shared__ double hre[SCOPE];
    __shared__ double him[SCOPE];
    const double TWO_PI = 6.283185307179586476925286766559;
    int t = threadIdx.x;
    if (t < SCOPE) {
        double re = 0.0, im = 0.0;
        for (int n = 0; n < SCOPE; ++n) {
            double x = (n == 0 ? 1.0 : 0.0) - (double)f[n];
            double ang = -TWO_PI * (double)(t * n) / (double)SCOPE;
            re += x * cos(ang);
            im += x * sin(ang);
        }
        double d = re * re + im * im;
        hre[t] = re / d;
        him[t] = -im / d;
    }
    __syncthreads();
    if (t < SCOPE) {
        double acc = 0.0;
        for (int k = 0; k < SCOPE; ++k) {
            double ang = TWO_PI * (double)(k * t) / (double)SCOPE;
            acc += hre[k] * cos(ang) - him[k] * sin(ang);
        }
        g[t] = (float)(acc / (double)SCOPE);
    }
}

// ---------------------------------------------------------------------------
// Kernel 2: circulant matmul via MFMA.
//   OUT[rows x 63] = A[rows x 63] * GM[63 x 63],  GM[k][n] = g[(n-k) mod 63]
// bf16 3-pass split: OUT = Ahi*Bhi + Ahi*Blo + Alo*Bhi  (alo*glo ~2e-3, dropped)
// K padded to 64 with B[63][*] = 0  -> A's k=63 over-read garbage * 0 = 0.
// N padded to 64; col 63 never stored.
//
// mfma_f32_16x16x32_bf16 fragments (lane l of the wave):
//   A[m][k]: m = l&15, k = 8*(l>>4) + j   (+32*kt), j = 0..7
//   B[k][n]: n = l&15, k = 8*(l>>4) + j   (+32*kt)
//   C[row][col]: col = l&15, row = 4*(l>>4) + i   [guide-verified, m89]
// B is stored PRE-SWIZZLED in fragment order Bf[nt][kt][l][j] so each lane's
// B-frag is one aligned 16B ds_read_b128 (conflict-free).
//
// Per block (256 thr = 4 waves, 128 rows): wave w owns rows 32w..32w+31
// = 2 M-tiles; 4 N-tiles x 2 K-steps x 3 passes = 48 MFMA/wave.
// Staging via GLL (r17 base, 95us); C written back to own rows of the tile
// (no barrier needed: per-wave LDS ordering), then coalesced float4 store.
// ---------------------------------------------------------------------------
__global__ void __launch_bounds__(BLOCK_THREADS)
circ_conv_kernel(const float* __restrict__ A,
                 const float* __restrict__ G,
                 float* __restrict__ O) {
    __shared__ __align__(16) float tile[TILE_ELEMS + 16];  // +pad for k-overread
    __shared__ __align__(16) __bf16 Bhi[4096];             // [nt][kt][lane][8]
    __shared__ __align__(16) __bf16 Blo[4096];
    __shared__ float gs[SCOPE];

    const int tid = threadIdx.x;
    const int w   = tid >> 6;        // wave in block
    const int l   = tid & 63;        // lane in wave
    const int c   = l & 15;          // fragment column index
    const int q   = l >> 4;          // fragment k-group / row-group

    const long long row0 = (long long)blockIdx.x * ROWS_PER_BLOCK;
    const float* __restrict__ src = A + row0 * SCOPE;
    float* __restrict__ dst       = O + row0 * SCOPE;

    if (tid < SCOPE) gs[tid] = G[tid];

    // ---- stage 128 rows (2016 float4) via async global->LDS ----
    const float4* src4 = (const float4*)src;
    float4* w4 = (float4*)tile;
#pragma unroll
    for (int it = 0; it < 7; ++it)
        GLL(src4 + it * 256 + tid, w4 + it * 256 + tid);
    if (tid < 224)
        GLL(src4 + 1792 + tid, w4 + 1792 + tid);

    __syncthreads();   // gs visible, tile ready (vmcnt drained)

    // ---- build B fragments (16 entries/thread/matrix) ----
#pragma unroll
    for (int f = tid; f < 4096; f += BLOCK_THREADS) {
        const int j  = f & 7;
        const int fl = (f >> 3) & 63;
        const int kt = (f >> 9) & 1;
        const int nt = f >> 10;
        const int k  = 8 * (fl >> 4) + j + 32 * kt;
        const int n  = 16 * nt + (fl & 15);
        float v = (k < SCOPE && n < SCOPE) ? gs[(n - k + SCOPE) % SCOPE] : 0.0f;
        __bf16 h = (__bf16)v;
        Bhi[f] = h;
        Blo[f] = (__bf16)(v - (float)h);
    }

    __syncthreads();   // B fragments ready

    // ---- A fragments: rows 32w + 16mt + c, 8 floats at koff = 8q + 32kt ----
    v8bf ahi[2][2], alo[2][2];   // [mt][kt]
#pragma unroll
    for (int mt = 0; mt < 2; ++mt) {
#pragma unroll
        for (int kt = 0; kt < 2; ++kt) {
            const float* ap = tile + (32 * w + 16 * mt + c) * SCOPE
                            + 8 * q + 32 * kt;
#pragma unroll
            for (int j = 0; j < 8; ++j) {
                float v = ap[j];                 // k=63 garbage * B[63]=0 -> ok
                __bf16 h = (__bf16)v;
                ahi[mt][kt][j] = h;
                alo[mt][kt][j] = (__bf16)(v - (float)h);
            }
        }
    }

    // ---- 4 N-tiles x 2 M-tiles x (2 kt x 3 passes) MFMA ----
#pragma unroll
    for (int nt = 0; nt < 4; ++nt) {
        v8bf bh[2], bl[2];
#pragma unroll
        for (int kt = 0; kt < 2; ++kt) {
            const int base = ((nt * 2 + kt) * 64 + l) * 8;
            bh[kt] = *reinterpret_cast<const v8bf*>(&Bhi[base]);
            bl[kt] = *reinterpret_cast<const v8bf*>(&Blo[base]);
        }
#pragma unroll
        for (int mt = 0; mt < 2; ++mt) {
            f32x4 acc = {0.f, 0.f, 0.f, 0.f};
#pragma unroll
            for (int kt = 0; kt < 2; ++kt) {
                acc = __builtin_amdgcn_mfma_f32_16x16x32_bf16(ahi[mt][kt], bh[kt], acc, 0, 0, 0);
                acc = __builtin_amdgcn_mfma_f32_16x16x32_bf16(ahi[mt][kt], bl[kt], acc, 0, 0, 0);
                acc = __builtin_amdgcn_mfma_f32_16x16x32_bf16(alo[mt][kt], bh[kt], acc, 0, 0, 0);
            }
            // C write: col = 16nt + c, rows 32w + 16mt + 4q + i (own rows)
            const int col = 16 * nt + c;
            if (col < SCOPE) {
                float* cp = tile + (32 * w + 16 * mt + 4 * q) * SCOPE + col;
#pragma unroll
                for (int i = 0; i < 4; ++i)
                    cp[i * SCOPE] = acc[i];
            }
        }
    }

    __syncthreads();   // all outputs in tile

    // ---- coalesced float4 store ----
    float4* dst4 = (float4*)dst;
#pragma unroll
    for (int it = 0; it < 7; ++it)
        dst4[it * 256 + tid] = w4[it * 256 + tid];
    if (tid < 224)
        dst4[1792 + tid] = w4[1792 + tid];
}

// ---------------------------------------------------------------------------
extern "C" void kernel_launch(void* const* d_in, const int* in_sizes, int n_in,
                              void* d_out, int out_size, void* d_ws, size_t ws_size,
                              hipStream_t stream) {
    const float* activations = (const float*)d_in[0];
    const float* filt        = (const float*)d_in[1];
    float* out               = (float*)d_out;
    float* g                 = (float*)d_ws;   // 63 floats of scratch

    hipLaunchKernelGGL(compute_inverse_filter, dim3(1), dim3(64), 0, stream,
                       filt, g);

    const long long total = (long long)in_sizes[0];
    const long long rows  = total / SCOPE;                 // 524288
    const int blocks      = (int)(rows / ROWS_PER_BLOCK);  // 4096, exact

    hipLaunchKernelGGL(circ_conv_kernel, dim3(blocks), dim3(BLOCK_THREADS), 0,
                       stream, activations, g, out);
}